// Round 3
// baseline (318.756 us; speedup 1.0000x reference)
//
#include <hip/hip_runtime.h>
#include <math.h>

// FeatureLabelLoss: features (B,C,D) f32, embeddings (C,D) f32, labels (B,C) f32
// -> scalar f32 loss.
// BW-bound on the streaming read of features (327.7 MB). VALU is ~13% of the
// HBM time budget, so reduction/transcendental cost is irrelevant.
// This round: single fused kernel (last-block-done reduction, no second
// dispatch) + 5000 finer-grained blocks to smooth the dispatch tail.

constexpr int B = 32;
constexpr int C = 5000;
constexpr int D = 512;                 // 512 floats = 2 float4 per lane
constexpr int NROWS = B * C;           // 160000
constexpr float EPS_NORM = 1e-12f;
constexpr float EPS_LOG = 1e-6f;

constexpr int WPB = 4;                 // waves per block
constexpr int THREADS = WPB * 64;      // 256
constexpr int B_PER_WAVE = B / WPB;    // 8
constexpr int MAIN_BLOCKS = C;         // 5000: one c-column per block

__global__ __launch_bounds__(THREADS) void fll_fused(
    const float* __restrict__ feat,
    const float* __restrict__ emb,
    const float* __restrict__ labels,
    float* __restrict__ partial,
    unsigned int* __restrict__ counter,
    float* __restrict__ out)
{
    const int lane = threadIdx.x & 63;
    const int wid  = threadIdx.x >> 6;
    const int c    = blockIdx.x;

    // Embedding row for this c: loaded once per wave (L1-shared within block)
    const float4* er = reinterpret_cast<const float4*>(emb + (size_t)c * D);
    const float4 e0 = er[lane];
    const float4 e1 = er[lane + 64];

    float ess = e0.x * e0.x + e0.y * e0.y + e0.z * e0.z + e0.w * e0.w
              + e1.x * e1.x + e1.y * e1.y + e1.z * e1.z + e1.w * e1.w;
    #pragma unroll
    for (int off = 32; off > 0; off >>= 1) ess += __shfl_xor(ess, off, 64);
    const float inv_ne = 1.0f / fmaxf(sqrtf(ess), EPS_NORM);

    const size_t bstride = (size_t)C * D;
    const float* fbase = feat + (size_t)(wid * B_PER_WAVE) * bstride + (size_t)c * D;
    const float* lbase = labels + (size_t)(wid * B_PER_WAVE) * C + c;

    float wacc = 0.0f;  // identical across all lanes of the wave

    #pragma unroll 4
    for (int i = 0; i < B_PER_WAVE; ++i) {
        const float4* fr = reinterpret_cast<const float4*>(fbase + (size_t)i * bstride);
        const float4 f0 = fr[lane];
        const float4 f1 = fr[lane + 64];

        float dot = f0.x * e0.x + f0.y * e0.y + f0.z * e0.z + f0.w * e0.w
                  + f1.x * e1.x + f1.y * e1.y + f1.z * e1.z + f1.w * e1.w;
        float fss = f0.x * f0.x + f0.y * f0.y + f0.z * f0.z + f0.w * f0.w
                  + f1.x * f1.x + f1.y * f1.y + f1.z * f1.z + f1.w * f1.w;

        #pragma unroll
        for (int off = 32; off > 0; off >>= 1) {
            dot += __shfl_xor(dot, off, 64);
            fss += __shfl_xor(fss, off, 64);
        }

        const float inv_nf = 1.0f / fmaxf(sqrtf(fss), EPS_NORM);
        const float sim = dot * inv_nf * inv_ne;
        const float lab = lbase[(size_t)i * C];  // wave-uniform
        const float S = 0.5f * (1.0f + sim) + EPS_LOG;
        const float T = 1.0f
            - ((float)(C - 1) / (float)C) * fabsf(1.0f / (float)(C - 1) + sim)
            + EPS_LOG;
        // labels are exactly 0.0 or 1.0
        wacc += logf(lab > 0.5f ? S : T);
    }

    __shared__ float wsum[WPB];
    __shared__ bool isLast;
    if (lane == 0) wsum[wid] = wacc;
    __syncthreads();
    if (threadIdx.x == 0) {
        float s = 0.0f;
        #pragma unroll
        for (int w = 0; w < WPB; ++w) s += wsum[w];
        partial[blockIdx.x] = s;
        __threadfence();                       // release: partial visible device-wide
        unsigned old = atomicAdd(counter, 1u); // device-scope
        isLast = (old == (unsigned)(gridDim.x - 1));
    }
    __syncthreads();

    if (isLast) {
        __threadfence();  // acquire: invalidate stale cached partials
        double acc = 0.0;
        for (int i = threadIdx.x; i < MAIN_BLOCKS; i += THREADS)
            acc += (double)partial[i];
        #pragma unroll
        for (int off = 32; off > 0; off >>= 1) acc += __shfl_xor(acc, off, 64);

        __shared__ double s[WPB];
        if (lane == 0) s[wid] = acc;
        __syncthreads();
        if (threadIdx.x == 0) {
            double tot = 0.0;
            #pragma unroll
            for (int w = 0; w < WPB; ++w) tot += s[w];
            out[0] = (float)(-tot / (double)NROWS);
        }
    }
}

extern "C" void kernel_launch(void* const* d_in, const int* in_sizes, int n_in,
                              void* d_out, int out_size, void* d_ws, size_t ws_size,
                              hipStream_t stream) {
    const float* feat   = (const float*)d_in[0];   // (B, C, D)
    const float* emb    = (const float*)d_in[1];   // (C, D)
    const float* labels = (const float*)d_in[2];   // (B, C)
    float* out = (float*)d_out;

    float* partial = (float*)d_ws;                          // MAIN_BLOCKS floats
    unsigned int* counter = (unsigned int*)((char*)d_ws + ((MAIN_BLOCKS * 4 + 63) & ~63));

    // zero the arrival counter every call (graph-capturable memset node)
    hipMemsetAsync(counter, 0, sizeof(unsigned int), stream);

    fll_fused<<<MAIN_BLOCKS, THREADS, 0, stream>>>(feat, emb, labels,
                                                   partial, counter, out);
}

// Round 5
// 157.241 us; speedup vs baseline: 2.0272x; 2.0272x over previous
//
#include <hip/hip_runtime.h>
#include <math.h>

// FeatureLabelLoss: features (B,C,D) f32, embeddings (C,D) f32, labels (B,C) f32
// -> scalar f32 loss.
// BW-bound on the streaming read of features (327.7 MB).
// R2 lesson: per-block __threadfence() (buffer_wbl2 L2 scan) serialized the
// chip -> two-kernel structure restored.
// R3/R4: perfectly balanced one-pass grid: 1280 blocks x 5 waves = 6400 waves,
// 25 contiguous-c rows per wave => exactly 5 blocks/CU, no dispatch tail.
// Features streamed contiguously with nontemporal loads; embeddings hit L2/L3.
// R4 fix: __builtin_nontemporal_load needs a native ext_vector type, not
// HIP_vector_type<float,4>.

typedef float f32x4 __attribute__((ext_vector_type(4)));

constexpr int B = 32;
constexpr int C = 5000;
constexpr int D = 512;                 // 512 floats = 2 f32x4 per lane
constexpr int NROWS = B * C;           // 160000
constexpr float EPS_LOG = 1e-6f;

constexpr int ROWS_PER_WAVE = 25;
constexpr int SEGS_PER_B = C / ROWS_PER_WAVE;      // 200
constexpr int NWAVES = B * SEGS_PER_B;             // 6400
constexpr int WPB = 5;                             // waves per block
constexpr int THREADS = WPB * 64;                  // 320
constexpr int MAIN_BLOCKS = NWAVES / WPB;          // 1280 = 5 blocks/CU exactly

__global__ __launch_bounds__(THREADS, 7) void fll_main(
    const float* __restrict__ feat,
    const float* __restrict__ emb,
    const float* __restrict__ labels,
    float* __restrict__ partial)
{
    const int lane = threadIdx.x & 63;
    const int wid  = threadIdx.x >> 6;
    const int gw   = blockIdx.x * WPB + wid;       // 0 .. 6399
    const int b    = gw / SEGS_PER_B;
    const int c0   = (gw % SEGS_PER_B) * ROWS_PER_WAVE;

    const float* fbase = feat + ((size_t)b * C + c0) * D;   // 50 KB contiguous
    const float* ebase = emb + (size_t)c0 * D;
    const float* lbase = labels + (size_t)b * C + c0;

    float wacc = 0.0f;  // identical across all lanes of the wave

    #pragma unroll 2
    for (int r = 0; r < ROWS_PER_WAVE; ++r) {
        const f32x4* fr = reinterpret_cast<const f32x4*>(fbase + (size_t)r * D);
        const f32x4* er = reinterpret_cast<const f32x4*>(ebase + (size_t)r * D);
        const f32x4 f0 = __builtin_nontemporal_load(fr + lane);
        const f32x4 f1 = __builtin_nontemporal_load(fr + lane + 64);
        const f32x4 e0 = er[lane];
        const f32x4 e1 = er[lane + 64];

        float dot = f0.x * e0.x + f0.y * e0.y + f0.z * e0.z + f0.w * e0.w
                  + f1.x * e1.x + f1.y * e1.y + f1.z * e1.z + f1.w * e1.w;
        float fss = f0.x * f0.x + f0.y * f0.y + f0.z * f0.z + f0.w * f0.w
                  + f1.x * f1.x + f1.y * f1.y + f1.z * f1.z + f1.w * f1.w;
        float ess = e0.x * e0.x + e0.y * e0.y + e0.z * e0.z + e0.w * e0.w
                  + e1.x * e1.x + e1.y * e1.y + e1.z * e1.z + e1.w * e1.w;

        // three independent butterflies, interleaved for latency overlap
        #pragma unroll
        for (int off = 32; off > 0; off >>= 1) {
            dot += __shfl_xor(dot, off, 64);
            fss += __shfl_xor(fss, off, 64);
            ess += __shfl_xor(ess, off, 64);
        }

        // norms ~sqrt(512); EPS_NORM (1e-12) can never bind -> combined form exact
        const float sim = dot / sqrtf(fss * ess);
        const float lab = lbase[r];                 // wave-uniform
        const float S = 0.5f * (1.0f + sim) + EPS_LOG;
        const float T = 1.0f
            - ((float)(C - 1) / (float)C) * fabsf(1.0f / (float)(C - 1) + sim)
            + EPS_LOG;
        // labels are exactly 0.0 or 1.0
        wacc += logf(lab > 0.5f ? S : T);
    }

    __shared__ float wsum[WPB];
    if (lane == 0) wsum[wid] = wacc;
    __syncthreads();
    if (threadIdx.x == 0) {
        float s = 0.0f;
        #pragma unroll
        for (int w = 0; w < WPB; ++w) s += wsum[w];
        partial[blockIdx.x] = s;  // written fresh every launch
    }
}

__global__ __launch_bounds__(256) void fll_reduce(
    const float* __restrict__ partial, float* __restrict__ out)
{
    const int lane = threadIdx.x & 63;
    const int wave = threadIdx.x >> 6;
    double acc = 0.0;
    for (int i = threadIdx.x; i < MAIN_BLOCKS; i += 256) acc += (double)partial[i];

    #pragma unroll
    for (int off = 32; off > 0; off >>= 1) acc += __shfl_xor(acc, off, 64);

    __shared__ double s[4];
    if (lane == 0) s[wave] = acc;
    __syncthreads();
    if (threadIdx.x == 0) {
        double tot = 0.0;
        #pragma unroll
        for (int w = 0; w < 4; ++w) tot += s[w];
        out[0] = (float)(-tot / (double)NROWS);
    }
}

extern "C" void kernel_launch(void* const* d_in, const int* in_sizes, int n_in,
                              void* d_out, int out_size, void* d_ws, size_t ws_size,
                              hipStream_t stream) {
    const float* feat   = (const float*)d_in[0];   // (B, C, D)
    const float* emb    = (const float*)d_in[1];   // (C, D)
    const float* labels = (const float*)d_in[2];   // (B, C)
    float* out = (float*)d_out;
    float* partial = (float*)d_ws;                 // MAIN_BLOCKS floats

    fll_main<<<MAIN_BLOCKS, THREADS, 0, stream>>>(feat, emb, labels, partial);
    fll_reduce<<<1, 256, 0, stream>>>(partial, out);
}

// Round 6
// 144.041 us; speedup vs baseline: 2.2130x; 1.0916x over previous
//
#include <hip/hip_runtime.h>
#include <math.h>

// FeatureLabelLoss: features (B,C,D) f32, embeddings (C,D) f32, labels (B,C) f32
// -> scalar f32 loss.  BW-bound on the 327.7 MB features stream.
//
// R1 (65.2 us) structure is the proven baseline: emb row in registers,
// b-strided feature streaming. R4's contiguous-c + NT-load bundle was 2.4x
// WORSE (and was perfectly balanced -> balance was never the limiter).
// R5 changes vs R1:
//   1. Deferred batch reduction: per-lane dot/fss accumulators for 8 rows,
//      ONE 17-value butterfly session at wave end -> streaming phase is pure
//      loads+FMAs (no dependent DS chain between load batches).
//   2. Fence-free single-kernel finish: per-block double atomicAdd (device
//      scope, memory-side coherent; NO __threadfence -- R2's buffer_wbl2
//      disaster) + arrival counter; last block re-reads sum and writes out.
//      16-byte memset node replaces the 2nd kernel (+launch gap).

typedef float f32x4 __attribute__((ext_vector_type(4)));

constexpr int B = 32;
constexpr int C = 5000;
constexpr int D = 512;                 // 512 floats = 2 f32x4 per lane
constexpr int NROWS = B * C;           // 160000
constexpr float EPS_LOG = 1e-6f;

constexpr int WAVES_PER_C = 4;
constexpr int B_PER_WAVE = B / WAVES_PER_C;   // 8 rows per wave
constexpr int WPB = 4;                        // waves per block (one c per block)
constexpr int THREADS = WPB * 64;             // 256
constexpr int NBLOCKS = C;                    // 5000

__global__ __launch_bounds__(THREADS, 6) void fll_main(
    const float* __restrict__ feat,
    const float* __restrict__ emb,
    const float* __restrict__ labels,
    double* __restrict__ dsum,
    unsigned int* __restrict__ cnt,
    float* __restrict__ out)
{
    const int lane = threadIdx.x & 63;
    const int wid  = threadIdx.x >> 6;
    const int c    = blockIdx.x;
    const int q    = wid;              // which 8-row quarter of B

    // Embedding row for this c: registers, reused 8x (block-wide L1 for 3 waves)
    const f32x4* er = reinterpret_cast<const f32x4*>(emb + (size_t)c * D);
    const f32x4 e0 = er[lane];
    const f32x4 e1 = er[lane + 64];
    float ess = e0.x * e0.x + e0.y * e0.y + e0.z * e0.z + e0.w * e0.w
              + e1.x * e1.x + e1.y * e1.y + e1.z * e1.z + e1.w * e1.w;

    const size_t bstr = (size_t)C * D;
    const float* fb = feat + (size_t)(q * B_PER_WAVE) * bstr + (size_t)c * D;
    const float* lb = labels + (size_t)(q * B_PER_WAVE) * C + c;

    // ---- streaming phase: pure loads + FMAs, no cross-lane ops ----
    float dacc[B_PER_WAVE], facc[B_PER_WAVE];
    #pragma unroll
    for (int i = 0; i < B_PER_WAVE; ++i) {   // fully unrolled -> static indices
        const f32x4* fr = reinterpret_cast<const f32x4*>(fb + (size_t)i * bstr);
        const f32x4 f0 = fr[lane];
        const f32x4 f1 = fr[lane + 64];
        dacc[i] = f0.x * e0.x + f0.y * e0.y + f0.z * e0.z + f0.w * e0.w
                + f1.x * e1.x + f1.y * e1.y + f1.z * e1.z + f1.w * e1.w;
        facc[i] = f0.x * f0.x + f0.y * f0.y + f0.z * f0.z + f0.w * f0.w
                + f1.x * f1.x + f1.y * f1.y + f1.z * f1.z + f1.w * f1.w;
    }

    // ---- batched butterfly: 17 independent chains per step, fully pipelined
    #pragma unroll
    for (int off = 32; off > 0; off >>= 1) {
        ess += __shfl_xor(ess, off, 64);
        #pragma unroll
        for (int i = 0; i < B_PER_WAVE; ++i) {
            dacc[i] += __shfl_xor(dacc[i], off, 64);
            facc[i] += __shfl_xor(facc[i], off, 64);
        }
    }

    // ---- per-row loss (all lanes compute identically; labels are 0/1) ----
    float wacc = 0.0f;
    #pragma unroll
    for (int i = 0; i < B_PER_WAVE; ++i) {
        const float sim = dacc[i] / sqrtf(facc[i] * ess);
        const float lab = lb[(size_t)i * C];        // wave-uniform
        const float S = 0.5f * (1.0f + sim) + EPS_LOG;
        const float T = 1.0f
            - ((float)(C - 1) / (float)C) * fabsf(1.0f / (float)(C - 1) + sim)
            + EPS_LOG;
        wacc += logf(lab > 0.5f ? S : T);
    }

    // ---- block gather + fence-free atomic finish ----
    __shared__ float wsum[WPB];
    if (lane == 0) wsum[wid] = wacc;
    __syncthreads();
    if (threadIdx.x == 0) {
        const double part = (double)wsum[0] + (double)wsum[1]
                          + (double)wsum[2] + (double)wsum[3];
        atomicAdd(dsum, part);                       // device-scope, memory-side
        asm volatile("s_waitcnt vmcnt(0)" ::: "memory");  // order sum before cnt
        const unsigned old = atomicAdd(cnt, 1u);
        if (old == (unsigned)(NBLOCKS - 1)) {
            // all sum-adds complete (each block's sum preceded its cnt-add)
            const double total = atomicAdd(dsum, 0.0);   // coherent fresh read
            out[0] = (float)(-total / (double)NROWS);
        }
    }
}

extern "C" void kernel_launch(void* const* d_in, const int* in_sizes, int n_in,
                              void* d_out, int out_size, void* d_ws, size_t ws_size,
                              hipStream_t stream) {
    const float* feat   = (const float*)d_in[0];   // (B, C, D)
    const float* emb    = (const float*)d_in[1];   // (C, D)
    const float* labels = (const float*)d_in[2];   // (B, C)
    float* out = (float*)d_out;

    double* dsum      = (double*)d_ws;                   // offset 0, 8 B
    unsigned int* cnt = (unsigned int*)((char*)d_ws + 8);

    hipMemsetAsync(d_ws, 0, 16, stream);   // zero sum+counter (capturable node)
    fll_main<<<NBLOCKS, THREADS, 0, stream>>>(feat, emb, labels, dsum, cnt, out);
}

// Round 7
// 65.548 us; speedup vs baseline: 4.8629x; 2.1975x over previous
//
#include <hip/hip_runtime.h>
#include <math.h>

// FeatureLabelLoss: features (B,C,D) f32, embeddings (C,D) f32, labels (B,C) f32
// -> scalar f32 loss.  BW-bound on the 327.7 MB features stream.
//
// Proven structure (R1, 65.2 us): emb row in registers, b-strided feature
// streaming, per-row butterfly, partial[] + tiny reduce kernel.
// R2 lesson: NO per-block __threadfence (buffer_wbl2 serializes the chip).
// R5 lesson: NO same-address global atomics (5000 fp64 adds ~ +79 us).
// R6 single-variable change vs R1: tail-free grid. 1280 blocks x 4 waves
// = 5120 waves, exactly 5 blocks/CU -> ALL blocks co-resident, no second
// dispatch wavefront. Waves grid-stride over 20000 (c, b-quarter) units.

typedef float f32x4 __attribute__((ext_vector_type(4)));

constexpr int B = 32;
constexpr int C = 5000;
constexpr int D = 512;                 // 512 floats = 2 f32x4 per lane
constexpr int NROWS = B * C;           // 160000
constexpr float EPS_LOG = 1e-6f;

constexpr int WPB = 4;                 // waves per block
constexpr int THREADS = WPB * 64;      // 256
constexpr int NBLOCKS = 1280;          // = 5 blocks/CU exactly, all resident
constexpr int NWAVES_TOT = NBLOCKS * WPB;   // 5120
constexpr int QROWS = 8;               // rows per work unit
constexpr int UNITS = NROWS / QROWS;   // 20000 = (c, quarter) pairs

__global__ __launch_bounds__(THREADS) void fll_main(
    const float* __restrict__ feat,
    const float* __restrict__ emb,
    const float* __restrict__ labels,
    float* __restrict__ partial)
{
    const int lane = threadIdx.x & 63;
    const int wid  = threadIdx.x >> 6;
    const int gw   = blockIdx.x * WPB + wid;   // 0 .. 5119

    const size_t bstr = (size_t)C * D;
    float wacc = 0.0f;   // identical across lanes of the wave

    // units u, u+5120, u+10240, u+15360  (4 or 3 per wave)
    for (int u = gw; u < UNITS; u += NWAVES_TOT) {
        const int c = u >> 2;            // consecutive waves share c -> L1 reuse
        const int q = u & 3;             // which 8-row quarter of B

        // embedding row for this c: registers, reused for 8 feature rows
        const f32x4* er = reinterpret_cast<const f32x4*>(emb + (size_t)c * D);
        const f32x4 e0 = er[lane];
        const f32x4 e1 = er[lane + 64];
        float ess = e0.x * e0.x + e0.y * e0.y + e0.z * e0.z + e0.w * e0.w
                  + e1.x * e1.x + e1.y * e1.y + e1.z * e1.z + e1.w * e1.w;
        #pragma unroll
        for (int off = 32; off > 0; off >>= 1) ess += __shfl_xor(ess, off, 64);

        const float* fb = feat + (size_t)(q * QROWS) * bstr + (size_t)c * D;
        const float* lb = labels + (size_t)(q * QROWS) * C + c;

        #pragma unroll 4
        for (int i = 0; i < QROWS; ++i) {
            const f32x4* fr = reinterpret_cast<const f32x4*>(fb + (size_t)i * bstr);
            const f32x4 f0 = fr[lane];
            const f32x4 f1 = fr[lane + 64];

            float dot = f0.x * e0.x + f0.y * e0.y + f0.z * e0.z + f0.w * e0.w
                      + f1.x * e1.x + f1.y * e1.y + f1.z * e1.z + f1.w * e1.w;
            float fss = f0.x * f0.x + f0.y * f0.y + f0.z * f0.z + f0.w * f0.w
                      + f1.x * f1.x + f1.y * f1.y + f1.z * f1.z + f1.w * f1.w;

            #pragma unroll
            for (int off = 32; off > 0; off >>= 1) {
                dot += __shfl_xor(dot, off, 64);
                fss += __shfl_xor(fss, off, 64);
            }

            // norms ~sqrt(512) >> EPS_NORM -> combined form exact (validated)
            const float sim = dot / sqrtf(fss * ess);
            const float lab = lb[(size_t)i * C];    // wave-uniform
            const float S = 0.5f * (1.0f + sim) + EPS_LOG;
            const float T = 1.0f
                - ((float)(C - 1) / (float)C) * fabsf(1.0f / (float)(C - 1) + sim)
                + EPS_LOG;
            // labels are exactly 0.0 or 1.0
            wacc += logf(lab > 0.5f ? S : T);
        }
    }

    __shared__ float wsum[WPB];
    if (lane == 0) wsum[wid] = wacc;
    __syncthreads();
    if (threadIdx.x == 0) {
        float s = 0.0f;
        #pragma unroll
        for (int w = 0; w < WPB; ++w) s += wsum[w];
        partial[blockIdx.x] = s;   // written fresh every launch
    }
}

__global__ __launch_bounds__(256) void fll_reduce(
    const float* __restrict__ partial, float* __restrict__ out)
{
    const int lane = threadIdx.x & 63;
    const int wave = threadIdx.x >> 6;
    double acc = 0.0;
    for (int i = threadIdx.x; i < NBLOCKS; i += 256) acc += (double)partial[i];

    #pragma unroll
    for (int off = 32; off > 0; off >>= 1) acc += __shfl_xor(acc, off, 64);

    __shared__ double s[4];
    if (lane == 0) s[wave] = acc;
    __syncthreads();
    if (threadIdx.x == 0) {
        double tot = 0.0;
        #pragma unroll
        for (int w = 0; w < 4; ++w) tot += s[w];
        out[0] = (float)(-tot / (double)NROWS);
    }
}

extern "C" void kernel_launch(void* const* d_in, const int* in_sizes, int n_in,
                              void* d_out, int out_size, void* d_ws, size_t ws_size,
                              hipStream_t stream) {
    const float* feat   = (const float*)d_in[0];   // (B, C, D)
    const float* emb    = (const float*)d_in[1];   // (C, D)
    const float* labels = (const float*)d_in[2];   // (B, C)
    float* out = (float*)d_out;
    float* partial = (float*)d_ws;                 // NBLOCKS floats

    fll_main<<<NBLOCKS, THREADS, 0, stream>>>(feat, emb, labels, partial);
    fll_reduce<<<1, 256, 0, stream>>>(partial, out);
}